// Round 14
// baseline (3728.131 us; speedup 1.0000x reference)
//
#include <hip/hip_runtime.h>

typedef unsigned short u16;
typedef unsigned int u32;
typedef unsigned long long u64;
typedef short v8s __attribute__((ext_vector_type(8)));
typedef float v4f __attribute__((ext_vector_type(4)));

// T=256, B=64, NIN=H=512, NOUT=512, 4H=2048, T*B=16384
#define TT 256
#define BB 64
#define HH 512
#define G4 2048
#define MTB 16384

static __device__ __forceinline__ float bf2f(u16 u) {
    u32 x = ((u32)u) << 16;
    union { u32 i; float f; } c; c.i = x; return c.f;
}
static __device__ __forceinline__ u16 f2bf(float f) {
    union { float f; u32 i; } c; c.f = f;
    u32 u = c.i;
    u += 0x7fffu + ((u >> 16) & 1u);   // RNE
    return (u16)(u >> 16);
}

__global__ __launch_bounds__(256) void cvt_bf16(const float* __restrict__ src,
                                                u16* __restrict__ dst, int n) {
    int i = blockIdx.x * blockDim.x + threadIdx.x;
    int stride = gridDim.x * blockDim.x;
    for (int j = i * 4; j < n; j += stride * 4) {
        float4 v = *reinterpret_cast<const float4*>(src + j);
        ushort4 o;
        o.x = f2bf(v.x); o.y = f2bf(v.y); o.z = f2bf(v.z); o.w = f2bf(v.w);
        *reinterpret_cast<ushort4*>(dst + j) = o;
    }
}

// C[M][N] = A[M][K] * B[N][K]^T (+ bias).  A,B bf16 K-contiguous; 128x128 tile, BK=64,
// 4 waves in 2x2, each wave 64x64 = 4x4 16x16x32 fragments. M,N,K multiples of 128 assumed.
template<bool OUT_BF16, bool BIAS_M>
__global__ __launch_bounds__(256) void gemm_bt(const u16* __restrict__ A,
                                               const u16* __restrict__ Bm,
                                               void* __restrict__ Cv,
                                               const float* __restrict__ bias1,
                                               const float* __restrict__ bias2,
                                               int M, int N, int K) {
    __shared__ u16 lds_a[128 * 64];
    __shared__ u16 lds_b[128 * 64];
    const int tid = threadIdx.x, lane = tid & 63;
    const int m0 = blockIdx.y * 128, n0 = blockIdx.x * 128;
    const int wid = tid >> 6, wm = wid >> 1, wn = wid & 1;
    v4f acc[4][4] = {};

    const int srow  = tid >> 3;
    const int skoff = (tid & 7) * 8;
    const u16* Ag = A + (size_t)(m0 + srow) * K + skoff;
    const u16* Bg = Bm + (size_t)(n0 + srow) * K + skoff;
    u16* la = lds_a + srow * 64 + skoff;
    u16* lb = lds_b + srow * 64 + skoff;

    for (int k0 = 0; k0 < K; k0 += 64) {
        #pragma unroll
        for (int q = 0; q < 4; ++q) {
            *reinterpret_cast<v8s*>(la + q * 32 * 64) =
                *reinterpret_cast<const v8s*>(Ag + (size_t)q * 32 * K + k0);
            *reinterpret_cast<v8s*>(lb + q * 32 * 64) =
                *reinterpret_cast<const v8s*>(Bg + (size_t)q * 32 * K + k0);
        }
        __syncthreads();
        #pragma unroll
        for (int kk = 0; kk < 2; ++kk) {
            v8s af[4], bfr[4];
            #pragma unroll
            for (int i = 0; i < 4; ++i)
                af[i] = *reinterpret_cast<const v8s*>(
                    lds_a + (wm * 64 + i * 16 + (lane & 15)) * 64 + kk * 32 + (lane >> 4) * 8);
            #pragma unroll
            for (int i = 0; i < 4; ++i)
                bfr[i] = *reinterpret_cast<const v8s*>(
                    lds_b + (wn * 64 + i * 16 + (lane & 15)) * 64 + kk * 32 + (lane >> 4) * 8);
            #pragma unroll
            for (int i = 0; i < 4; ++i)
                #pragma unroll
                for (int j = 0; j < 4; ++j)
                    acc[i][j] = __builtin_amdgcn_mfma_f32_16x16x32_bf16(af[i], bfr[j], acc[i][j], 0, 0, 0);
        }
        __syncthreads();
    }
    #pragma unroll
    for (int i = 0; i < 4; ++i) {
        #pragma unroll
        for (int j = 0; j < 4; ++j) {
            #pragma unroll
            for (int r = 0; r < 4; ++r) {
                int m = m0 + wm * 64 + i * 16 + (lane >> 4) * 4 + r;
                int n = n0 + wn * 64 + j * 16 + (lane & 15);
                float v = acc[i][j][r];
                if (BIAS_M) { v += bias1[m]; if (bias2) v += bias2[m]; }
                else        { v += bias1[n]; }
                if (OUT_BF16) ((u16*)Cv)[(size_t)m * N + n] = f2bf(v);
                else          ((float*)Cv)[(size_t)m * N + n] = v;
            }
        }
    }
}

static __device__ __forceinline__ float sigm(float x) { return 1.f / (1.f + __expf(-x)); }
static __device__ __forceinline__ float tanh_(float x) { return 2.f / (1.f + __expf(-2.f * x)) - 1.f; }

static __device__ __forceinline__ u64 ald(const u64* p) {
    return __hip_atomic_load(p, __ATOMIC_RELAXED, __HIP_MEMORY_SCOPE_AGENT);
}
static __device__ __forceinline__ u32 packw(u64 q) {   // (tag|bf16, tag|bf16) -> bf16x2
    return ((u32)q & 0xFFFFu) | ((u32)(q >> 32) << 16);
}

// Persistent bidirectional LSTM recurrence — tagged-ring exchange, hybrid retry.
// R3-R12: flag-based agent sync = 3 serial IC legs (drain, flag, poll) ~4us/step,
// invariant to traffic/publish/packing. R13 (XCD-local L2): HUNG — termination must
// never depend on block->XCD placement (G16). This kernel fuses detect+data into ONE
// IC trip (R7's tagged scheme, numerically proven) and fixes R7's two failures:
//   1. ring of 4 time-slices (1MB total, IC-resident) instead of 67MB tagged buffer.
//      Safety: a block at step s+2 implies every block published s+1, hence finished
//      reading s -> a 4-deep ring is never overwritten while readable.
//   2. hybrid retry: first pass batch-loads all 16 fragments + validates tags per-kk
//      (wave-uniform __all mask, static indexing); MFMA valid ones immediately;
//      stragglers re-load ONLY their 32B fragment (narrow ~1us detect, no storm).
// Producer: gates -> 2xu64 tagged ring stores + 1 plain h_all store (for FC),
// fire-and-forget: NO drain, NO flag. 64 blocks x 256 thr: bx>>5=dir, &31=cg; wave nf
// owns b=nf*16..+15, all 4 gates, K=512; w_hh slice (64KB) LDS-resident.
__global__ __launch_bounds__(256, 2) void lstm_persist(
    const u16* __restrict__ w_hh,        // [2][2048][512]
    const u16* __restrict__ xgT,         // [2][2048][16384]  col = t*64+b
    u16* __restrict__ h_all,             // [256*64][1024] untagged (FC input)
    u32* __restrict__ ring)              // [4][64][1024] tagged (t<<16 | bf16)
{
    __shared__ u16 wlds[4 * 16 * 64 * 8];    // [G][kk][lane][8 bf16] = 64 KB
    const int bx = blockIdx.x;
    const int d = bx >> 5, cg = bx & 31;
    const int lane = threadIdx.x & 63, nf = threadIdx.x >> 6;
    const int lrow = lane & 15, lk = lane >> 4;
    const int b = nf * 16 + lrow;        // this lane's batch column

    // ---- stage A fragments into LDS (once): wave nf fills gate G = nf ----
    {
        const int G = nf;
        const u16* wrow = w_hh + ((size_t)d * G4 + G * HH + cg * 16 + lrow) * HH + lk * 8;
        #pragma unroll
        for (int kk = 0; kk < 16; ++kk)
            *reinterpret_cast<v8s*>(&wlds[((G * 16 + kk) * 64 + lane) * 8]) =
                *reinterpret_cast<const v8s*>(wrow + kk * 32);
    }
    __syncthreads();

    float c[4] = {0.f, 0.f, 0.f, 0.f};
    float xg[4][4];

    // xg for step 0
    {
        const int t0 = d ? (TT - 1) : 0;
        const u16* xgb = xgT + (size_t)d * G4 * MTB + (size_t)t0 * BB + b;
        #pragma unroll
        for (int G = 0; G < 4; ++G)
            #pragma unroll
            for (int r = 0; r < 4; ++r)
                xg[G][r] = bf2f(xgb[(size_t)(G * HH + cg * 16 + lk * 4 + r) * MTB]);
    }

    for (int s = 0; s < TT; ++s) {
        const int t = d ? (TT - 1 - s) : s;
        v4f acc[4] = {};
        if (s > 0) {
            const int tprev = d ? (t + 1) : (t - 1);
            const u64 expq = (u64)((u32)tprev << 16);
            const u32* rp = ring + ((size_t)(tprev & 3) * BB + b) * 1024 + d * HH + lk * 8;
            v8s bf_[16];
            u32 valid = 0;
            // ---- pass 1: batched load of all 16 fragments, validate, MFMA valid ----
            #pragma unroll
            for (int kk = 0; kk < 16; ++kk) {
                const u64* p = (const u64*)(rp + kk * 32);
                u64 q0 = ald(p), q1 = ald(p + 1), q2 = ald(p + 2), q3 = ald(p + 3);
                u64 bad = ((q0 ^ expq) | (q1 ^ expq) | (q2 ^ expq) | (q3 ^ expq))
                          & 0x00000000FFFF0000ULL;
                union { u32 w[4]; v8s v; } P;
                P.w[0] = packw(q0); P.w[1] = packw(q1);
                P.w[2] = packw(q2); P.w[3] = packw(q3);
                bf_[kk] = P.v;
                if (__all(bad == 0)) valid |= 1u << kk;
            }
            #pragma unroll
            for (int kk = 0; kk < 16; ++kk)
                if (valid & (1u << kk)) {
                    #pragma unroll
                    for (int G = 0; G < 4; ++G) {
                        v8s af = *reinterpret_cast<const v8s*>(
                            &wlds[((G * 16 + kk) * 64 + lane) * 8]);
                        acc[G] = __builtin_amdgcn_mfma_f32_16x16x32_bf16(af, bf_[kk], acc[G], 0, 0, 0);
                    }
                }
            // ---- straggler loop: narrow per-fragment reload (32B/lane), MFMA inline ----
            while (valid != 0xFFFFu) {
                #pragma unroll
                for (int kk = 0; kk < 16; ++kk)
                    if (!(valid & (1u << kk))) {
                        const u64* p = (const u64*)(rp + kk * 32);
                        u64 q0 = ald(p), q1 = ald(p + 1), q2 = ald(p + 2), q3 = ald(p + 3);
                        u64 bad = ((q0 ^ expq) | (q1 ^ expq) | (q2 ^ expq) | (q3 ^ expq))
                                  & 0x00000000FFFF0000ULL;
                        if (__all(bad == 0)) {
                            union { u32 w[4]; v8s v; } P;
                            P.w[0] = packw(q0); P.w[1] = packw(q1);
                            P.w[2] = packw(q2); P.w[3] = packw(q3);
                            #pragma unroll
                            for (int G = 0; G < 4; ++G) {
                                v8s af = *reinterpret_cast<const v8s*>(
                                    &wlds[((G * 16 + kk) * 64 + lane) * 8]);
                                acc[G] = __builtin_amdgcn_mfma_f32_16x16x32_bf16(af, P.v, acc[G], 0, 0, 0);
                            }
                            valid |= 1u << kk;
                        }
                    }
            }
        }
        // ---- gates + state update (all in this lane) ----
        const u32 tg = (u32)t << 16;
        u32 hw[4];
        ushort4 hout;
        #pragma unroll
        for (int r = 0; r < 4; ++r) {
            float pi = acc[0][r] + xg[0][r];
            float pf = acc[1][r] + xg[1][r];
            float pg = acc[2][r] + xg[2][r];
            float po = acc[3][r] + xg[3][r];
            float iv = sigm(pi), fv = sigm(pf), gv = tanh_(pg), ov = sigm(po);
            float cc = fv * c[r] + iv * gv;
            c[r] = cc;
            u16 hv = f2bf(ov * tanh_(cc));
            hw[r] = tg | (u32)hv;
            ((u16*)&hout)[r] = hv;
        }
        // ---- fire-and-forget stores: tagged ring (sync) + plain h_all (FC) ----
        const int j0 = cg * 16 + lk * 4;
        u64* rq = (u64*)(ring + ((size_t)(t & 3) * BB + b) * 1024 + d * HH + j0);
        __hip_atomic_store(rq,     (u64)hw[0] | ((u64)hw[1] << 32),
                           __ATOMIC_RELAXED, __HIP_MEMORY_SCOPE_AGENT);
        __hip_atomic_store(rq + 1, (u64)hw[2] | ((u64)hw[3] << 32),
                           __ATOMIC_RELAXED, __HIP_MEMORY_SCOPE_AGENT);
        union { ushort4 v; u64 q; } hu; hu.v = hout;
        *reinterpret_cast<u64*>(h_all + ((size_t)t * BB + b) * 1024 + d * HH + j0) = hu.q;
        // ---- prefetch next step's xg (retires under next consume pass) ----
        if (s + 1 < TT) {
            const int tn = d ? (TT - 2 - s) : (s + 1);
            const u16* xgb = xgT + (size_t)d * G4 * MTB + (size_t)tn * BB + b;
            #pragma unroll
            for (int G = 0; G < 4; ++G)
                #pragma unroll
                for (int r = 0; r < 4; ++r)
                    xg[G][r] = bf2f(xgb[(size_t)(G * HH + cg * 16 + lk * 4 + r) * MTB]);
        }
    }
}

extern "C" void kernel_launch(void* const* d_in, const int* in_sizes, int n_in,
                              void* d_out, int out_size, void* d_ws, size_t ws_size,
                              hipStream_t stream) {
    const float* x    = (const float*)d_in[0];
    const float* wihf = (const float*)d_in[1];
    const float* whhf = (const float*)d_in[2];
    const float* bihf = (const float*)d_in[3];
    const float* bhhf = (const float*)d_in[4];
    const float* wihb = (const float*)d_in[5];
    const float* whhb = (const float*)d_in[6];
    const float* bihb = (const float*)d_in[7];
    const float* bhhb = (const float*)d_in[8];
    const float* fcw  = (const float*)d_in[9];
    const float* fcb  = (const float*)d_in[10];

    char* ws = (char*)d_ws;
    size_t off = 0;
    auto alloc = [&](size_t bytes) {
        off = (off + 255) & ~(size_t)255;
        char* p = ws + off; off += bytes; return p;
    };
    u16* x_bf    = (u16*)alloc((size_t)MTB * 512 * 2);        // 16.8 MB
    u16* wih_bf  = (u16*)alloc((size_t)2 * G4 * 512 * 2);     // 4.2 MB
    u16* whh_bf  = (u16*)alloc((size_t)2 * G4 * 512 * 2);     // 4.2 MB
    u16* fcw_bf  = (u16*)alloc((size_t)512 * 1024 * 2);       // 1.0 MB
    u16* xgT     = (u16*)alloc((size_t)2 * G4 * MTB * 2);     // 134.2 MB
    u16* h_all   = (u16*)alloc((size_t)MTB * 1024 * 2);       // 33.6 MB
    u32* ring    = (u32*)alloc((size_t)4 * BB * 1024 * 4);    // 1.0 MB tagged ring
    (void)ws_size;

    // ---- convert inputs to bf16 ----
    cvt_bf16<<<1024, 256, 0, stream>>>(x, x_bf, MTB * 512);
    cvt_bf16<<<256, 256, 0, stream>>>(wihf, wih_bf, G4 * 512);
    cvt_bf16<<<256, 256, 0, stream>>>(wihb, wih_bf + (size_t)G4 * 512, G4 * 512);
    cvt_bf16<<<256, 256, 0, stream>>>(whhf, whh_bf, G4 * 512);
    cvt_bf16<<<256, 256, 0, stream>>>(whhb, whh_bf + (size_t)G4 * 512, G4 * 512);
    cvt_bf16<<<128, 256, 0, stream>>>(fcw, fcw_bf, 512 * 1024);

    // ---- clear stale ring tags (every call: graph replays reuse the buffer) ----
    hipMemsetAsync(ring, 0xFF, (size_t)4 * BB * 1024 * 4, stream);

    // ---- phase 1: xgT[d] = w_ih[d] @ x^T + (b_ih + b_hh), bf16 out, gate-major ----
    gemm_bt<true, true><<<dim3(MTB / 128, G4 / 128), 256, 0, stream>>>(
        wih_bf, x_bf, xgT, bihf, bhhf, G4, MTB, 512);
    gemm_bt<true, true><<<dim3(MTB / 128, G4 / 128), 256, 0, stream>>>(
        wih_bf + (size_t)G4 * 512, x_bf, xgT + (size_t)G4 * MTB, bihb, bhhb, G4, MTB, 512);

    // ---- phase 2: persistent recurrence, tagged-ring exchange ----
    lstm_persist<<<64, 256, 0, stream>>>(whh_bf, xgT, h_all, ring);

    // ---- phase 3: out = h_all @ fc_w^T + fc_b, fp32 out ----
    gemm_bt<false, false><<<dim3(512 / 128, MTB / 128), 256, 0, stream>>>(
        h_all, fcw_bf, d_out, fcb, nullptr, MTB, 512, 1024);
}

// Round 15
// 3125.848 us; speedup vs baseline: 1.1927x; 1.1927x over previous
//
#include <hip/hip_runtime.h>

typedef unsigned short u16;
typedef unsigned int u32;
typedef unsigned long long u64;
typedef short v8s __attribute__((ext_vector_type(8)));
typedef float v4f __attribute__((ext_vector_type(4)));

// T=256, B=64, NIN=H=512, NOUT=512, 4H=2048, T*B=16384
#define TT 256
#define BB 64
#define HH 512
#define G4 2048
#define MTB 16384

static __device__ __forceinline__ float bf2f(u16 u) {
    u32 x = ((u32)u) << 16;
    union { u32 i; float f; } c; c.i = x; return c.f;
}
static __device__ __forceinline__ u16 f2bf(float f) {
    union { float f; u32 i; } c; c.f = f;
    u32 u = c.i;
    u += 0x7fffu + ((u >> 16) & 1u);   // RNE
    return (u16)(u >> 16);
}

__global__ __launch_bounds__(256) void cvt_bf16(const float* __restrict__ src,
                                                u16* __restrict__ dst, int n) {
    int i = blockIdx.x * blockDim.x + threadIdx.x;
    int stride = gridDim.x * blockDim.x;
    for (int j = i * 4; j < n; j += stride * 4) {
        float4 v = *reinterpret_cast<const float4*>(src + j);
        ushort4 o;
        o.x = f2bf(v.x); o.y = f2bf(v.y); o.z = f2bf(v.z); o.w = f2bf(v.w);
        *reinterpret_cast<ushort4*>(dst + j) = o;
    }
}

// C[M][N] = A[M][K] * B[N][K]^T (+ bias).  A,B bf16 K-contiguous; 128x128 tile, BK=64,
// 4 waves in 2x2, each wave 64x64 = 4x4 16x16x32 fragments. M,N,K multiples of 128 assumed.
template<bool OUT_BF16, bool BIAS_M>
__global__ __launch_bounds__(256) void gemm_bt(const u16* __restrict__ A,
                                               const u16* __restrict__ Bm,
                                               void* __restrict__ Cv,
                                               const float* __restrict__ bias1,
                                               const float* __restrict__ bias2,
                                               int M, int N, int K) {
    __shared__ u16 lds_a[128 * 64];
    __shared__ u16 lds_b[128 * 64];
    const int tid = threadIdx.x, lane = tid & 63;
    const int m0 = blockIdx.y * 128, n0 = blockIdx.x * 128;
    const int wid = tid >> 6, wm = wid >> 1, wn = wid & 1;
    v4f acc[4][4] = {};

    const int srow  = tid >> 3;
    const int skoff = (tid & 7) * 8;
    const u16* Ag = A + (size_t)(m0 + srow) * K + skoff;
    const u16* Bg = Bm + (size_t)(n0 + srow) * K + skoff;
    u16* la = lds_a + srow * 64 + skoff;
    u16* lb = lds_b + srow * 64 + skoff;

    for (int k0 = 0; k0 < K; k0 += 64) {
        #pragma unroll
        for (int q = 0; q < 4; ++q) {
            *reinterpret_cast<v8s*>(la + q * 32 * 64) =
                *reinterpret_cast<const v8s*>(Ag + (size_t)q * 32 * K + k0);
            *reinterpret_cast<v8s*>(lb + q * 32 * 64) =
                *reinterpret_cast<const v8s*>(Bg + (size_t)q * 32 * K + k0);
        }
        __syncthreads();
        #pragma unroll
        for (int kk = 0; kk < 2; ++kk) {
            v8s af[4], bfr[4];
            #pragma unroll
            for (int i = 0; i < 4; ++i)
                af[i] = *reinterpret_cast<const v8s*>(
                    lds_a + (wm * 64 + i * 16 + (lane & 15)) * 64 + kk * 32 + (lane >> 4) * 8);
            #pragma unroll
            for (int i = 0; i < 4; ++i)
                bfr[i] = *reinterpret_cast<const v8s*>(
                    lds_b + (wn * 64 + i * 16 + (lane & 15)) * 64 + kk * 32 + (lane >> 4) * 8);
            #pragma unroll
            for (int i = 0; i < 4; ++i)
                #pragma unroll
                for (int j = 0; j < 4; ++j)
                    acc[i][j] = __builtin_amdgcn_mfma_f32_16x16x32_bf16(af[i], bfr[j], acc[i][j], 0, 0, 0);
        }
        __syncthreads();
    }
    #pragma unroll
    for (int i = 0; i < 4; ++i) {
        #pragma unroll
        for (int j = 0; j < 4; ++j) {
            #pragma unroll
            for (int r = 0; r < 4; ++r) {
                int m = m0 + wm * 64 + i * 16 + (lane >> 4) * 4 + r;
                int n = n0 + wn * 64 + j * 16 + (lane & 15);
                float v = acc[i][j][r];
                if (BIAS_M) { v += bias1[m]; if (bias2) v += bias2[m]; }
                else        { v += bias1[n]; }
                if (OUT_BF16) ((u16*)Cv)[(size_t)m * N + n] = f2bf(v);
                else          ((float*)Cv)[(size_t)m * N + n] = v;
            }
        }
    }
}

static __device__ __forceinline__ float sigm(float x) { return 1.f / (1.f + __expf(-x)); }
static __device__ __forceinline__ float tanh_(float x) { return 2.f / (1.f + __expf(-2.f * x)) - 1.f; }

static __device__ __forceinline__ u64 ald(const u64* p) {
    return __hip_atomic_load(p, __ATOMIC_RELAXED, __HIP_MEMORY_SCOPE_AGENT);
}
static __device__ __forceinline__ u32 packw(u64 q) {   // (tag|bf16, tag|bf16) -> bf16x2
    return ((u32)q & 0xFFFFu) | ((u32)(q >> 32) << 16);
}

// Persistent bidirectional LSTM recurrence — tagged-ring exchange, BATCHED waits.
// R7/R14 post-mortem: both tagged attempts ran at ~14us/step = 16 SERIAL IC round
// trips — the per-fragment __all() check forced a vmcnt wait per kk. The transport
// itself (1 fused IC trip; no producer drain; no flag leg) is the only mechanism
// that can beat R6's 3-leg flag chain (5.25us/step floor, invariant R3-R12).
// This round: issue ALL 64 ring u64 loads + 16 xg loads with no intervening uses,
// ONE s_waitcnt vmcnt(0), then validate/pack/MFMA from registers. Stragglers are
// re-loaded in BATCHED ROUNDS (all missing fragments per round, one wait per round)
// — each round costs 1 IC RTT regardless of count. Producer: 2 tagged u64 ring
// stores + 1 plain h_all store, fire-and-forget (acks retire inside next step's
// load window). Ring: 4 slices x [64][1024] u32 (1MB); depth-4 safety: a block at
// step s+2 observed every block's s+1 data, which implies all finished reading s.
// Ring 0xFF-memset per call (stale tags never match). 64 blocks x 256 thr:
// bx>>5=dir, &31=cg; wave nf owns b=nf*16..+15, all 4 gates, K=512; w_hh slice
// (64KB) LDS-resident as [G][kk][lane]*16B fragments.
__global__ __launch_bounds__(256, 1) void lstm_persist(
    const u16* __restrict__ w_hh,        // [2][2048][512]
    const u16* __restrict__ xgT,         // [2][2048][16384]  col = t*64+b
    u16* __restrict__ h_all,             // [256*64][1024] untagged (FC input)
    u32* __restrict__ ring)              // [4][64][1024] tagged (t<<16 | bf16)
{
    __shared__ u16 wlds[4 * 16 * 64 * 8];    // [G][kk][lane][8 bf16] = 64 KB
    const int bx = blockIdx.x;
    const int d = bx >> 5, cg = bx & 31;
    const int lane = threadIdx.x & 63, nf = threadIdx.x >> 6;
    const int lrow = lane & 15, lk = lane >> 4;
    const int b = nf * 16 + lrow;        // this lane's batch column

    // ---- stage A fragments into LDS (once): wave nf fills gate G = nf ----
    {
        const int G = nf;
        const u16* wrow = w_hh + ((size_t)d * G4 + G * HH + cg * 16 + lrow) * HH + lk * 8;
        #pragma unroll
        for (int kk = 0; kk < 16; ++kk)
            *reinterpret_cast<v8s*>(&wlds[((G * 16 + kk) * 64 + lane) * 8]) =
                *reinterpret_cast<const v8s*>(wrow + kk * 32);
    }
    __syncthreads();

    float c[4] = {0.f, 0.f, 0.f, 0.f};

    for (int s = 0; s < TT; ++s) {
        const int t = d ? (TT - 1 - s) : s;

        // ---- issue THIS step's xg loads first (share the batched wait) ----
        u16 xgr[16];
        {
            const u16* xgb = xgT + (size_t)d * G4 * MTB + (size_t)t * BB + b;
            #pragma unroll
            for (int G = 0; G < 4; ++G)
                #pragma unroll
                for (int r = 0; r < 4; ++r)
                    xgr[G * 4 + r] = xgb[(size_t)(G * HH + cg * 16 + lk * 4 + r) * MTB];
        }

        v4f acc[4] = {};
        if (s > 0) {
            const int tprev = d ? (t + 1) : (t - 1);
            const u64 expq = (u64)((u32)tprev << 16);
            const u32* rp = ring + ((size_t)(tprev & 3) * BB + b) * 1024 + d * HH + lk * 8;
            // ---- pass 1: issue ALL 64 u64 loads, ONE wait ----
            u64 raw[64];
            #pragma unroll
            for (int kk = 0; kk < 16; ++kk) {
                const u64* p = (const u64*)(rp + kk * 32);
                raw[kk * 4 + 0] = ald(p + 0);
                raw[kk * 4 + 1] = ald(p + 1);
                raw[kk * 4 + 2] = ald(p + 2);
                raw[kk * 4 + 3] = ald(p + 3);
            }
            asm volatile("s_waitcnt vmcnt(0)" ::: "memory");
            // ---- validate + pack + MFMA valid fragments (pure VALU/MFMA) ----
            u32 valid = 0;
            #pragma unroll
            for (int kk = 0; kk < 16; ++kk) {
                u64 q0 = raw[kk * 4], q1 = raw[kk * 4 + 1],
                    q2 = raw[kk * 4 + 2], q3 = raw[kk * 4 + 3];
                u64 bad = ((q0 ^ expq) | (q1 ^ expq) | (q2 ^ expq) | (q3 ^ expq))
                          & 0x00000000FFFF0000ULL;
                if (__all(bad == 0)) {
                    union { u32 w[4]; v8s v; } P;
                    P.w[0] = packw(q0); P.w[1] = packw(q1);
                    P.w[2] = packw(q2); P.w[3] = packw(q3);
                    #pragma unroll
                    for (int G = 0; G < 4; ++G) {
                        v8s af = *reinterpret_cast<const v8s*>(
                            &wlds[((G * 16 + kk) * 64 + lane) * 8]);
                        acc[G] = __builtin_amdgcn_mfma_f32_16x16x32_bf16(af, P.v, acc[G], 0, 0, 0);
                    }
                    valid |= 1u << kk;
                }
            }
            // ---- straggler rounds: batch-reload ALL missing, one wait per round ----
            while (valid != 0xFFFFu) {
                #pragma unroll
                for (int kk = 0; kk < 16; ++kk)
                    if (!(valid & (1u << kk))) {
                        const u64* p = (const u64*)(rp + kk * 32);
                        raw[kk * 4 + 0] = ald(p + 0);
                        raw[kk * 4 + 1] = ald(p + 1);
                        raw[kk * 4 + 2] = ald(p + 2);
                        raw[kk * 4 + 3] = ald(p + 3);
                    }
                asm volatile("s_waitcnt vmcnt(0)" ::: "memory");
                #pragma unroll
                for (int kk = 0; kk < 16; ++kk)
                    if (!(valid & (1u << kk))) {
                        u64 q0 = raw[kk * 4], q1 = raw[kk * 4 + 1],
                            q2 = raw[kk * 4 + 2], q3 = raw[kk * 4 + 3];
                        u64 bad = ((q0 ^ expq) | (q1 ^ expq) | (q2 ^ expq) | (q3 ^ expq))
                                  & 0x00000000FFFF0000ULL;
                        if (__all(bad == 0)) {
                            union { u32 w[4]; v8s v; } P;
                            P.w[0] = packw(q0); P.w[1] = packw(q1);
                            P.w[2] = packw(q2); P.w[3] = packw(q3);
                            #pragma unroll
                            for (int G = 0; G < 4; ++G) {
                                v8s af = *reinterpret_cast<const v8s*>(
                                    &wlds[((G * 16 + kk) * 64 + lane) * 8]);
                                acc[G] = __builtin_amdgcn_mfma_f32_16x16x32_bf16(af, P.v, acc[G], 0, 0, 0);
                            }
                            valid |= 1u << kk;
                        }
                    }
            }
        }
        // ---- gates + state update (all in this lane) ----
        const u32 tg = (u32)t << 16;
        u32 hw[4];
        ushort4 hout;
        #pragma unroll
        for (int r = 0; r < 4; ++r) {
            float pi = acc[0][r] + bf2f(xgr[0 * 4 + r]);
            float pf = acc[1][r] + bf2f(xgr[1 * 4 + r]);
            float pg = acc[2][r] + bf2f(xgr[2 * 4 + r]);
            float po = acc[3][r] + bf2f(xgr[3 * 4 + r]);
            float iv = sigm(pi), fv = sigm(pf), gv = tanh_(pg), ov = sigm(po);
            float cc = fv * c[r] + iv * gv;
            c[r] = cc;
            u16 hv = f2bf(ov * tanh_(cc));
            hw[r] = tg | (u32)hv;
            ((u16*)&hout)[r] = hv;
        }
        // ---- fire-and-forget: tagged ring (sync) + plain h_all (FC) ----
        const int j0 = cg * 16 + lk * 4;
        u64* rq = (u64*)(ring + ((size_t)(t & 3) * BB + b) * 1024 + d * HH + j0);
        __hip_atomic_store(rq,     (u64)hw[0] | ((u64)hw[1] << 32),
                           __ATOMIC_RELAXED, __HIP_MEMORY_SCOPE_AGENT);
        __hip_atomic_store(rq + 1, (u64)hw[2] | ((u64)hw[3] << 32),
                           __ATOMIC_RELAXED, __HIP_MEMORY_SCOPE_AGENT);
        union { ushort4 v; u64 q; } hu; hu.v = hout;
        *reinterpret_cast<u64*>(h_all + ((size_t)t * BB + b) * 1024 + d * HH + j0) = hu.q;
    }
}

extern "C" void kernel_launch(void* const* d_in, const int* in_sizes, int n_in,
                              void* d_out, int out_size, void* d_ws, size_t ws_size,
                              hipStream_t stream) {
    const float* x    = (const float*)d_in[0];
    const float* wihf = (const float*)d_in[1];
    const float* whhf = (const float*)d_in[2];
    const float* bihf = (const float*)d_in[3];
    const float* bhhf = (const float*)d_in[4];
    const float* wihb = (const float*)d_in[5];
    const float* whhb = (const float*)d_in[6];
    const float* bihb = (const float*)d_in[7];
    const float* bhhb = (const float*)d_in[8];
    const float* fcw  = (const float*)d_in[9];
    const float* fcb  = (const float*)d_in[10];

    char* ws = (char*)d_ws;
    size_t off = 0;
    auto alloc = [&](size_t bytes) {
        off = (off + 255) & ~(size_t)255;
        char* p = ws + off; off += bytes; return p;
    };
    u16* x_bf    = (u16*)alloc((size_t)MTB * 512 * 2);        // 16.8 MB
    u16* wih_bf  = (u16*)alloc((size_t)2 * G4 * 512 * 2);     // 4.2 MB
    u16* whh_bf  = (u16*)alloc((size_t)2 * G4 * 512 * 2);     // 4.2 MB
    u16* fcw_bf  = (u16*)alloc((size_t)512 * 1024 * 2);       // 1.0 MB
    u16* xgT     = (u16*)alloc((size_t)2 * G4 * MTB * 2);     // 134.2 MB
    u16* h_all   = (u16*)alloc((size_t)MTB * 1024 * 2);       // 33.6 MB
    u32* ring    = (u32*)alloc((size_t)4 * BB * 1024 * 4);    // 1.0 MB tagged ring
    (void)ws_size;

    // ---- convert inputs to bf16 ----
    cvt_bf16<<<1024, 256, 0, stream>>>(x, x_bf, MTB * 512);
    cvt_bf16<<<256, 256, 0, stream>>>(wihf, wih_bf, G4 * 512);
    cvt_bf16<<<256, 256, 0, stream>>>(wihb, wih_bf + (size_t)G4 * 512, G4 * 512);
    cvt_bf16<<<256, 256, 0, stream>>>(whhf, whh_bf, G4 * 512);
    cvt_bf16<<<256, 256, 0, stream>>>(whhb, whh_bf + (size_t)G4 * 512, G4 * 512);
    cvt_bf16<<<128, 256, 0, stream>>>(fcw, fcw_bf, 512 * 1024);

    // ---- clear stale ring tags (every call: graph replays reuse the buffer) ----
    hipMemsetAsync(ring, 0xFF, (size_t)4 * BB * 1024 * 4, stream);

    // ---- phase 1: xgT[d] = w_ih[d] @ x^T + (b_ih + b_hh), bf16 out, gate-major ----
    gemm_bt<true, true><<<dim3(MTB / 128, G4 / 128), 256, 0, stream>>>(
        wih_bf, x_bf, xgT, bihf, bhhf, G4, MTB, 512);
    gemm_bt<true, true><<<dim3(MTB / 128, G4 / 128), 256, 0, stream>>>(
        wih_bf + (size_t)G4 * 512, x_bf, xgT + (size_t)G4 * MTB, bihb, bhhb, G4, MTB, 512);

    // ---- phase 2: persistent recurrence, tagged-ring exchange (batched waits) ----
    lstm_persist<<<64, 256, 0, stream>>>(whh_bf, xgT, h_all, ring);

    // ---- phase 3: out = h_all @ fc_w^T + fc_b, fp32 out ----
    gemm_bt<false, false><<<dim3(512 / 128, MTB / 128), 256, 0, stream>>>(
        h_all, fcw_bf, d_out, fcb, nullptr, MTB, 512, 1024);
}

// Round 16
// 2514.605 us; speedup vs baseline: 1.4826x; 1.2431x over previous
//
#include <hip/hip_runtime.h>

typedef unsigned short u16;
typedef unsigned int u32;
typedef unsigned long long u64;
typedef short v8s __attribute__((ext_vector_type(8)));
typedef float v4f __attribute__((ext_vector_type(4)));

// T=256, B=64, NIN=H=512, NOUT=512, 4H=2048, T*B=16384
#define TT 256
#define BB 64
#define HH 512
#define G4 2048
#define MTB 16384

static __device__ __forceinline__ float bf2f(u16 u) {
    u32 x = ((u32)u) << 16;
    union { u32 i; float f; } c; c.i = x; return c.f;
}
static __device__ __forceinline__ u16 f2bf(float f) {
    union { float f; u32 i; } c; c.f = f;
    u32 u = c.i;
    u += 0x7fffu + ((u >> 16) & 1u);   // RNE
    return (u16)(u >> 16);
}

__global__ __launch_bounds__(256) void cvt_bf16(const float* __restrict__ src,
                                                u16* __restrict__ dst, int n) {
    int i = blockIdx.x * blockDim.x + threadIdx.x;
    int stride = gridDim.x * blockDim.x;
    for (int j = i * 4; j < n; j += stride * 4) {
        float4 v = *reinterpret_cast<const float4*>(src + j);
        ushort4 o;
        o.x = f2bf(v.x); o.y = f2bf(v.y); o.z = f2bf(v.z); o.w = f2bf(v.w);
        *reinterpret_cast<ushort4*>(dst + j) = o;
    }
}

// C[M][N] = A[M][K] * B[N][K]^T (+ bias).  A,B bf16 K-contiguous; 128x128 tile, BK=64,
// 4 waves in 2x2, each wave 64x64 = 4x4 16x16x32 fragments. M,N,K multiples of 128 assumed.
template<bool OUT_BF16, bool BIAS_M>
__global__ __launch_bounds__(256) void gemm_bt(const u16* __restrict__ A,
                                               const u16* __restrict__ Bm,
                                               void* __restrict__ Cv,
                                               const float* __restrict__ bias1,
                                               const float* __restrict__ bias2,
                                               int M, int N, int K) {
    __shared__ u16 lds_a[128 * 64];
    __shared__ u16 lds_b[128 * 64];
    const int tid = threadIdx.x, lane = tid & 63;
    const int m0 = blockIdx.y * 128, n0 = blockIdx.x * 128;
    const int wid = tid >> 6, wm = wid >> 1, wn = wid & 1;
    v4f acc[4][4] = {};

    const int srow  = tid >> 3;
    const int skoff = (tid & 7) * 8;
    const u16* Ag = A + (size_t)(m0 + srow) * K + skoff;
    const u16* Bg = Bm + (size_t)(n0 + srow) * K + skoff;
    u16* la = lds_a + srow * 64 + skoff;
    u16* lb = lds_b + srow * 64 + skoff;

    for (int k0 = 0; k0 < K; k0 += 64) {
        #pragma unroll
        for (int q = 0; q < 4; ++q) {
            *reinterpret_cast<v8s*>(la + q * 32 * 64) =
                *reinterpret_cast<const v8s*>(Ag + (size_t)q * 32 * K + k0);
            *reinterpret_cast<v8s*>(lb + q * 32 * 64) =
                *reinterpret_cast<const v8s*>(Bg + (size_t)q * 32 * K + k0);
        }
        __syncthreads();
        #pragma unroll
        for (int kk = 0; kk < 2; ++kk) {
            v8s af[4], bfr[4];
            #pragma unroll
            for (int i = 0; i < 4; ++i)
                af[i] = *reinterpret_cast<const v8s*>(
                    lds_a + (wm * 64 + i * 16 + (lane & 15)) * 64 + kk * 32 + (lane >> 4) * 8);
            #pragma unroll
            for (int i = 0; i < 4; ++i)
                bfr[i] = *reinterpret_cast<const v8s*>(
                    lds_b + (wn * 64 + i * 16 + (lane & 15)) * 64 + kk * 32 + (lane >> 4) * 8);
            #pragma unroll
            for (int i = 0; i < 4; ++i)
                #pragma unroll
                for (int j = 0; j < 4; ++j)
                    acc[i][j] = __builtin_amdgcn_mfma_f32_16x16x32_bf16(af[i], bfr[j], acc[i][j], 0, 0, 0);
        }
        __syncthreads();
    }
    #pragma unroll
    for (int i = 0; i < 4; ++i) {
        #pragma unroll
        for (int j = 0; j < 4; ++j) {
            #pragma unroll
            for (int r = 0; r < 4; ++r) {
                int m = m0 + wm * 64 + i * 16 + (lane >> 4) * 4 + r;
                int n = n0 + wn * 64 + j * 16 + (lane & 15);
                float v = acc[i][j][r];
                if (BIAS_M) { v += bias1[m]; if (bias2) v += bias2[m]; }
                else        { v += bias1[n]; }
                if (OUT_BF16) ((u16*)Cv)[(size_t)m * N + n] = f2bf(v);
                else          ((float*)Cv)[(size_t)m * N + n] = v;
            }
        }
    }
}

static __device__ __forceinline__ float sigm(float x) { return 1.f / (1.f + __expf(-x)); }
static __device__ __forceinline__ float tanh_(float x) { return 2.f / (1.f + __expf(-2.f * x)) - 1.f; }

// Persistent bidirectional LSTM recurrence — DIRECTION-INTERLEAVED PHASES.
// R3-R15 established: the per-step sync cost is loads+compute+drain (~2.4us) plus
// publish->remote-detect propagation (~2.9us), the latter invariant to poll traffic,
// publish mechanism, flag granularity, and transport (tagged rings serialize at the
// compiler's vmcnt placement). Propagation is a WAIT, though — hideable under
// independent work. Here ONE wave executes dir-f's step (phase A), then dir-b's
// step (phase B), in program order: dir-f's propagation elapses during phase B and
// vice versa, so each poll finds its flags already visible.
// Fixes vs R9 (which tried this and lost): (1) h stores stay 8B ushort4 (R6 layout,
// WRITE_SIZE 35MB not 135MB); (2) xg prefetch for BOTH dirs issues once per
// iteration AFTER phase-B publish — the slot R6 proved free (shadow overlaps
// propagation), never between phases where it would shadow the next poll (R8 trap).
// 32 blocks x 256 threads: blockIdx.x = cg. Wave nf owns b = nf*16..+15 for BOTH
// dirs, all 4 gates, K=512. Weights for both dirs LDS-resident (2 x 64KB, static —
// R12 proved 128KB static compiles/runs). Sync domains (d,nf) unchanged from R6.
__global__ __launch_bounds__(256, 1) void lstm_persist(
    const u16* __restrict__ w_hh,        // [2][2048][512]
    const u16* __restrict__ xgT,         // [2][2048][16384]  col = t*64+b
    u16* __restrict__ h_all,             // [256*64][1024]
    unsigned* __restrict__ flags)        // [2][4][32] step counters, 128B/group
{
    __shared__ u16 wlds[2][4 * 16 * 64 * 8];     // [d][G][kk][lane][8 bf16] = 128 KB
    const int cg = blockIdx.x;                   // 0..31
    const int lane = threadIdx.x & 63, nf = threadIdx.x >> 6;
    const int lrow = lane & 15, lk = lane >> 4;
    const int b = nf * 16 + lrow;                // this lane's batch column

    // ---- stage A fragments into LDS (once): wave nf fills gate G=nf, both dirs ----
    #pragma unroll
    for (int dd = 0; dd < 2; ++dd) {
        const int G = nf;
        const u16* wrow = w_hh + ((size_t)dd * G4 + G * HH + cg * 16 + lrow) * HH + lk * 8;
        #pragma unroll
        for (int kk = 0; kk < 16; ++kk)
            *reinterpret_cast<v8s*>(&wlds[dd][((G * 16 + kk) * 64 + lane) * 8]) =
                *reinterpret_cast<const v8s*>(wrow + kk * 32);
    }
    __syncthreads();

    float c0[4] = {0.f, 0.f, 0.f, 0.f};          // dir-f cell state
    float c1[4] = {0.f, 0.f, 0.f, 0.f};          // dir-b cell state
    float xg[2][4][4];

    // xg for step 0, both dirs
    #pragma unroll
    for (int dd = 0; dd < 2; ++dd) {
        const int t0 = dd ? (TT - 1) : 0;
        const u16* xgb = xgT + (size_t)dd * G4 * MTB + (size_t)t0 * BB + b;
        #pragma unroll
        for (int G = 0; G < 4; ++G)
            #pragma unroll
            for (int r = 0; r < 4; ++r)
                xg[dd][G][r] = bf2f(xgb[(size_t)(G * HH + cg * 16 + lk * 4 + r) * MTB]);
    }

    for (int s = 0; s < TT; ++s) {
        #pragma unroll
        for (int dd = 0; dd < 2; ++dd) {         // phase A: dir-f, phase B: dir-b
            const int t = dd ? (TT - 1 - s) : s;
            float* c = dd ? c1 : c0;
            unsigned* fl = flags + (dd * 4 + nf) * 32;
            v4f acc[4] = {};
            if (s > 0) {
                // prefetch kk=0..3 A-fragments from LDS (overlaps detect)
                v8s af0[4][4];
                #pragma unroll
                for (int G = 0; G < 4; ++G)
                    #pragma unroll
                    for (int kk = 0; kk < 4; ++kk)
                        af0[G][kk] = *reinterpret_cast<const v8s*>(
                            &wlds[dd][((G * 16 + kk) * 64 + lane) * 8]);
                // poll: propagation already elapsed during the other dir's phase
                const unsigned tgt = (unsigned)s;
                while (true) {
                    unsigned fv = __hip_atomic_load(&fl[lane & 31],
                                                    __ATOMIC_RELAXED, __HIP_MEMORY_SCOPE_AGENT);
                    if (__all((int)(fv >= tgt))) break;
                }
                asm volatile("" ::: "memory");   // no load hoisting above the poll
                // h[tprev] B-fragments (16 x 16B, agent-coherent)
                const int tprev = dd ? (t + 1) : (t - 1);
                const u16* hp = h_all + ((size_t)tprev * BB + b) * 1024 + dd * HH + lk * 8;
                v8s bf_[16];
                #pragma unroll
                for (int kk = 0; kk < 16; ++kk) {
                    union { u64 w[2]; v8s v; } u;
                    const u16* p = hp + kk * 32;
                    u.w[0] = __hip_atomic_load((const u64*)p,
                                               __ATOMIC_RELAXED, __HIP_MEMORY_SCOPE_AGENT);
                    u.w[1] = __hip_atomic_load((const u64*)(p + 4),
                                               __ATOMIC_RELAXED, __HIP_MEMORY_SCOPE_AGENT);
                    bf_[kk] = u.v;
                }
                // MFMA: prefetched kk<4, then LDS-streamed kk=4..15
                #pragma unroll
                for (int kk = 0; kk < 4; ++kk)
                    #pragma unroll
                    for (int G = 0; G < 4; ++G)
                        acc[G] = __builtin_amdgcn_mfma_f32_16x16x32_bf16(af0[G][kk], bf_[kk], acc[G], 0, 0, 0);
                #pragma unroll
                for (int kk = 4; kk < 16; ++kk)
                    #pragma unroll
                    for (int G = 0; G < 4; ++G) {
                        v8s af = *reinterpret_cast<const v8s*>(
                            &wlds[dd][((G * 16 + kk) * 64 + lane) * 8]);
                        acc[G] = __builtin_amdgcn_mfma_f32_16x16x32_bf16(af, bf_[kk], acc[G], 0, 0, 0);
                    }
            }
            // gates + state update (all in this lane)
            ushort4 hout;
            #pragma unroll
            for (int r = 0; r < 4; ++r) {
                float pi = acc[0][r] + xg[dd][0][r];
                float pf = acc[1][r] + xg[dd][1][r];
                float pg = acc[2][r] + xg[dd][2][r];
                float po = acc[3][r] + xg[dd][3][r];
                float iv = sigm(pi), fv = sigm(pf), gv = tanh_(pg), ov = sigm(po);
                float cc = fv * c[r] + iv * gv;
                c[r] = cc;
                ((u16*)&hout)[r] = f2bf(ov * tanh_(cc));
            }
            // h[t][b][dd*512 + cg*16 + lk*4 .. +3]  (8B agent store)
            union { ushort4 v; u64 q; } hu; hu.v = hout;
            __hip_atomic_store((u64*)(
                    h_all + ((size_t)t * BB + b) * 1024 + dd * HH + cg * 16 + lk * 4),
                hu.q, __ATOMIC_RELAXED, __HIP_MEMORY_SCOPE_AGENT);
            // drain this wave's h store (only op outstanding), then publish
            asm volatile("s_waitcnt vmcnt(0)" ::: "memory");
            if (lane == 0)
                __hip_atomic_store(&fl[cg], (unsigned)(s + 1),
                                   __ATOMIC_RELAXED, __HIP_MEMORY_SCOPE_AGENT);
        }
        // ---- prefetch next step's xg for BOTH dirs: shadow overlaps propagation ----
        if (s + 1 < TT) {
            #pragma unroll
            for (int dd = 0; dd < 2; ++dd) {
                const int tn = dd ? (TT - 2 - s) : (s + 1);
                const u16* xgb = xgT + (size_t)dd * G4 * MTB + (size_t)tn * BB + b;
                #pragma unroll
                for (int G = 0; G < 4; ++G)
                    #pragma unroll
                    for (int r = 0; r < 4; ++r)
                        xg[dd][G][r] = bf2f(xgb[(size_t)(G * HH + cg * 16 + lk * 4 + r) * MTB]);
            }
        }
    }
}

extern "C" void kernel_launch(void* const* d_in, const int* in_sizes, int n_in,
                              void* d_out, int out_size, void* d_ws, size_t ws_size,
                              hipStream_t stream) {
    const float* x    = (const float*)d_in[0];
    const float* wihf = (const float*)d_in[1];
    const float* whhf = (const float*)d_in[2];
    const float* bihf = (const float*)d_in[3];
    const float* bhhf = (const float*)d_in[4];
    const float* wihb = (const float*)d_in[5];
    const float* whhb = (const float*)d_in[6];
    const float* bihb = (const float*)d_in[7];
    const float* bhhb = (const float*)d_in[8];
    const float* fcw  = (const float*)d_in[9];
    const float* fcb  = (const float*)d_in[10];

    char* ws = (char*)d_ws;
    size_t off = 0;
    auto alloc = [&](size_t bytes) {
        off = (off + 255) & ~(size_t)255;
        char* p = ws + off; off += bytes; return p;
    };
    u16* x_bf    = (u16*)alloc((size_t)MTB * 512 * 2);        // 16.8 MB
    u16* wih_bf  = (u16*)alloc((size_t)2 * G4 * 512 * 2);     // 4.2 MB
    u16* whh_bf  = (u16*)alloc((size_t)2 * G4 * 512 * 2);     // 4.2 MB
    u16* fcw_bf  = (u16*)alloc((size_t)512 * 1024 * 2);       // 1.0 MB
    u16* xgT     = (u16*)alloc((size_t)2 * G4 * MTB * 2);     // 134.2 MB
    u16* h_all   = (u16*)alloc((size_t)MTB * 1024 * 2);       // 33.6 MB
    unsigned* flags = (unsigned*)alloc(2 * 4 * 32 * sizeof(unsigned));
    (void)ws_size;

    // ---- convert inputs to bf16 ----
    cvt_bf16<<<1024, 256, 0, stream>>>(x, x_bf, MTB * 512);
    cvt_bf16<<<256, 256, 0, stream>>>(wihf, wih_bf, G4 * 512);
    cvt_bf16<<<256, 256, 0, stream>>>(wihb, wih_bf + (size_t)G4 * 512, G4 * 512);
    cvt_bf16<<<256, 256, 0, stream>>>(whhf, whh_bf, G4 * 512);
    cvt_bf16<<<256, 256, 0, stream>>>(whhb, whh_bf + (size_t)G4 * 512, G4 * 512);
    cvt_bf16<<<128, 256, 0, stream>>>(fcw, fcw_bf, 512 * 1024);

    // ---- phase 1: xgT[d] = w_ih[d] @ x^T + (b_ih + b_hh), bf16 out, gate-major ----
    gemm_bt<true, true><<<dim3(MTB / 128, G4 / 128), 256, 0, stream>>>(
        wih_bf, x_bf, xgT, bihf, bhhf, G4, MTB, 512);
    gemm_bt<true, true><<<dim3(MTB / 128, G4 / 128), 256, 0, stream>>>(
        wih_bf + (size_t)G4 * 512, x_bf, xgT + (size_t)G4 * MTB, bihb, bhhb, G4, MTB, 512);

    // ---- phase 2: persistent recurrence, direction-interleaved phases ----
    hipMemsetAsync(flags, 0, 2 * 4 * 32 * sizeof(unsigned), stream);
    lstm_persist<<<32, 256, 0, stream>>>(whh_bf, xgT, h_all, flags);

    // ---- phase 3: out = h_all @ fc_w^T + fc_b, fp32 out ----
    gemm_bt<false, false><<<dim3(512 / 128, MTB / 128), 256, 0, stream>>>(
        h_all, fcw_bf, d_out, fcb, nullptr, MTB, 512, 1024);
}